// Round 29
// baseline (161.254 us; speedup 1.0000x reference)
//
#include <hip/hip_runtime.h>
#include <stdint.h>

// B=4, T=2048, C=1024, H=16, HD=64
// apack/bpack/wprojp: fragment-linear bf16 ([rb16][kt32][lane][8])
// qbuf: [B*T][1024] bf16, PRE-SCALED by c=0.125*log2(e) ; kf/vf: 32x32x16 A-frag tiles
// attf: A-frag layout

typedef float f32x4 __attribute__((ext_vector_type(4)));
typedef float f32x16 __attribute__((ext_vector_type(16)));
typedef short s16x8 __attribute__((ext_vector_type(8)));
typedef unsigned short u16x4 __attribute__((ext_vector_type(4)));
typedef unsigned int u32x4 __attribute__((ext_vector_type(4)));
typedef unsigned int u32x2 __attribute__((ext_vector_type(2)));

__device__ __forceinline__ unsigned short f2b(float f) {
  unsigned u = __builtin_bit_cast(unsigned, f);
  u += 0x7fffu + ((u >> 16) & 1u);
  return (unsigned short)(u >> 16);
}

__device__ __forceinline__ unsigned cvtpk(float lo, float hi) {
  unsigned r;
  asm("v_cvt_pk_bf16_f32 %0, %1, %2" : "=v"(r) : "v"(lo), "v"(hi));
  return r;
}

// ---------------- fused fp32 [R][1024] -> fragment-linear bf16 pack (x, wqkv, wproj) ----------------
// out[rb][kt][lane][8] = in[rb*16 + (lane&15)][kt*32 + (lane>>4)*8 + j]
__global__ __launch_bounds__(256) void pack3_kernel(const float* __restrict__ x,
                                                    const float* __restrict__ wqkv,
                                                    const float* __restrict__ wproj,
                                                    unsigned short* __restrict__ apack,
                                                    unsigned short* __restrict__ bpack,
                                                    unsigned short* __restrict__ wprojp) {
  const float* in;
  unsigned short* out;
  int i;
  const int blk = blockIdx.x;
  if (blk < 4096) {
    in = x; out = apack; i = blk * 256 + threadIdx.x;
  } else if (blk < 4096 + 1536) {
    in = wqkv; out = bpack; i = (blk - 4096) * 256 + threadIdx.x;
  } else {
    in = wproj; out = wprojp; i = (blk - 4096 - 1536) * 256 + threadIdx.x;
  }
  int lane = i & 63, kt = (i >> 6) & 31, rb = i >> 11;
  int row = rb * 16 + (lane & 15);
  int col = kt * 32 + ((lane >> 4) << 3);
  const float4* p = reinterpret_cast<const float4*>(in + (size_t)row * 1024 + col);
  float4 v0 = p[0], v1 = p[1];
  s16x8 o;
  o[0] = (short)f2b(v0.x); o[1] = (short)f2b(v0.y);
  o[2] = (short)f2b(v0.z); o[3] = (short)f2b(v0.w);
  o[4] = (short)f2b(v1.x); o[5] = (short)f2b(v1.y);
  o[6] = (short)f2b(v1.z); o[7] = (short)f2b(v1.w);
  *(s16x8*)&out[(size_t)i * 8] = o;
}

// ---------------- QKV GEMM: fragment-direct, zero-LDS, barrier-free ----------------
// Full A/B ping-pong register double-buffer; UNIFORM base pointers + per-lane loff
// at load sites (SGPR saddr + VGPR voffset -> ~16 fewer VGPRs vs per-lane pointers).
// Q epilogue pre-scales by c = 0.125*log2(e).
__global__ __launch_bounds__(256) void gemm_fd(const unsigned short* __restrict__ ap,
                                               const unsigned short* __restrict__ bp,
                                               unsigned short* __restrict__ qbuf,
                                               unsigned short* __restrict__ kf,
                                               unsigned short* __restrict__ vf) {
  const int tid = threadIdx.x;
  const int l = tid & 63, w = tid >> 6;
  const int l15 = l & 15, lq = l >> 4;
  const int wr = w >> 1, wc = w & 1;
  const int xcd = blockIdx.x & 7;
  const int idx = blockIdx.x >> 3;
  const int m0 = (xcd * 8 + (idx & 7)) * 128;
  const int n0 = (idx >> 3) * 128;
  const int mb0 = (m0 >> 4) + wr * 4;
  const int nb0 = (n0 >> 4) + wc * 4;
  const int loff = l * 8;  // per-lane fragment slot (kept OUT of base pointers)

  const unsigned short* pa0 = ap + ((size_t)(mb0 + 0) * 32) * 512;
  const unsigned short* pa1 = ap + ((size_t)(mb0 + 1) * 32) * 512;
  const unsigned short* pa2 = ap + ((size_t)(mb0 + 2) * 32) * 512;
  const unsigned short* pa3 = ap + ((size_t)(mb0 + 3) * 32) * 512;
  const unsigned short* pb0 = bp + ((size_t)(nb0 + 0) * 32) * 512;
  const unsigned short* pb1 = bp + ((size_t)(nb0 + 1) * 32) * 512;
  const unsigned short* pb2 = bp + ((size_t)(nb0 + 2) * 32) * 512;
  const unsigned short* pb3 = bp + ((size_t)(nb0 + 3) * 32) * 512;

#define LDA(set, t)                                         \
  set[0] = *(const s16x8*)&pa0[(size_t)(t) * 512 + loff];   \
  set[1] = *(const s16x8*)&pa1[(size_t)(t) * 512 + loff];   \
  set[2] = *(const s16x8*)&pa2[(size_t)(t) * 512 + loff];   \
  set[3] = *(const s16x8*)&pa3[(size_t)(t) * 512 + loff];
#define LDB(set, t)                                         \
  set[0] = *(const s16x8*)&pb0[(size_t)(t) * 512 + loff];   \
  set[1] = *(const s16x8*)&pb1[(size_t)(t) * 512 + loff];   \
  set[2] = *(const s16x8*)&pb2[(size_t)(t) * 512 + loff];   \
  set[3] = *(const s16x8*)&pb3[(size_t)(t) * 512 + loff];
#define MFMA16(aset, bset)                                                                \
  __builtin_amdgcn_s_setprio(1);                                                          \
  _Pragma("unroll") for (int m = 0; m < 4; m++) _Pragma("unroll") for (int n = 0; n < 4;  \
                                                                       n++) acc[m][n] =  \
      __builtin_amdgcn_mfma_f32_16x16x32_bf16(aset[m], bset[n], acc[m][n], 0, 0, 0);      \
  __builtin_amdgcn_s_setprio(0);

  f32x4 acc[4][4] = {};
  s16x8 aA[4], bA[4], aB[4], bB[4];
  LDA(aA, 0); LDB(bA, 0);
  for (int t = 0; t < 32; t += 2) {
    const int t1 = t + 1;
    LDA(aB, t1); LDB(bB, t1);
    MFMA16(aA, bA);
    const int t2 = (t + 2 < 32) ? t + 2 : 31;
    LDA(aA, t2); LDB(bA, t2);
    MFMA16(aB, bB);
  }
#undef LDA
#undef LDB

  if (n0 < 1024) {
    const float c = 0.18033688011112042f;  // fold softmax scale into Q
#pragma unroll
    for (int m = 0; m < 4; m++)
#pragma unroll
      for (int n = 0; n < 4; n++)
#pragma unroll
        for (int r = 0; r < 4; r++) {
          int row = m0 + wr * 64 + m * 16 + lq * 4 + r;
          int col = n0 + wc * 64 + n * 16 + l15;
          qbuf[(size_t)row * 1024 + col] = f2b(acc[m][n][r] * c);
        }
  } else if (n0 < 2048) {
#pragma unroll
    for (int m = 0; m < 4; m++)
#pragma unroll
      for (int n = 0; n < 4; n++)
#pragma unroll
        for (int r = 0; r < 4; r++) {
          int key = m0 + wr * 64 + m * 16 + lq * 4 + r;
          int col = n0 - 1024 + wc * 64 + n * 16 + l15;  // h*64+d
          int hh = col >> 6, d = col & 63;
          int bb = key >> 11, k2 = key & 2047, t = k2 >> 5, ki = k2 & 31;
          int ds = d >> 4, hid = (d >> 3) & 1;
          kf[((size_t)((bb * 16 + hh) * 64 + t)) * 2048 + ds * 512 + (hid * 32 + ki) * 8 +
             (d & 7)] = f2b(acc[m][n][r]);
        }
  } else {
#pragma unroll
    for (int m = 0; m < 4; m++)
#pragma unroll
      for (int n = 0; n < 4; n++) {
        int key0 = m0 + wr * 64 + m * 16 + lq * 4;
        int col = n0 - 2048 + wc * 64 + n * 16 + l15;  // h*64+d
        int hh = col >> 6, d = col & 63;
        int bb = key0 >> 11, k2 = key0 & 2047, t = k2 >> 5, ki0 = k2 & 31;
        int ks = ki0 >> 4, hik = (ki0 >> 3) & 1, j0 = ki0 & 7;
        int dh = d >> 5;
        u16x4 o;
#pragma unroll
        for (int r = 0; r < 4; r++) o[r] = f2b(acc[m][n][r]);
        *(u16x4*)&vf[((size_t)((bb * 16 + hh) * 64 + t)) * 2048 + (dh * 2 + ks) * 512 +
                     (hik * 32 + (d & 31)) * 8 + j0] = o;
      }
  }
}

// ---------------- proj GEMM: fragment-direct, zero-LDS, barrier-free, f32+bias ----------------
__global__ __launch_bounds__(256) void gemm_pd(const unsigned short* __restrict__ ap,
                                               const unsigned short* __restrict__ bp,
                                               const float* __restrict__ bias,
                                               float* __restrict__ C) {
  const int tid = threadIdx.x;
  const int l = tid & 63, w = tid >> 6;
  const int l15 = l & 15, lq = l >> 4;
  const int wr = w >> 1, wc = w & 1;
  const int xcd = blockIdx.x & 7;
  const int idx = blockIdx.x >> 3;
  const int m0 = (xcd * 8 + (idx & 7)) * 128;
  const int n0 = (idx >> 3) * 128;
  const int mb0 = (m0 >> 4) + wr * 4;
  const int nb0 = (n0 >> 4) + wc * 4;
  const int loff = l * 8;

  const unsigned short* pa0 = ap + ((size_t)(mb0 + 0) * 32) * 512;
  const unsigned short* pa1 = ap + ((size_t)(mb0 + 1) * 32) * 512;
  const unsigned short* pa2 = ap + ((size_t)(mb0 + 2) * 32) * 512;
  const unsigned short* pa3 = ap + ((size_t)(mb0 + 3) * 32) * 512;
  const unsigned short* pb0 = bp + ((size_t)(nb0 + 0) * 32) * 512;
  const unsigned short* pb1 = bp + ((size_t)(nb0 + 1) * 32) * 512;
  const unsigned short* pb2 = bp + ((size_t)(nb0 + 2) * 32) * 512;
  const unsigned short* pb3 = bp + ((size_t)(nb0 + 3) * 32) * 512;

#define LDA(set, t)                                         \
  set[0] = *(const s16x8*)&pa0[(size_t)(t) * 512 + loff];   \
  set[1] = *(const s16x8*)&pa1[(size_t)(t) * 512 + loff];   \
  set[2] = *(const s16x8*)&pa2[(size_t)(t) * 512 + loff];   \
  set[3] = *(const s16x8*)&pa3[(size_t)(t) * 512 + loff];
#define LDB(set, t)                                         \
  set[0] = *(const s16x8*)&pb0[(size_t)(t) * 512 + loff];   \
  set[1] = *(const s16x8*)&pb1[(size_t)(t) * 512 + loff];   \
  set[2] = *(const s16x8*)&pb2[(size_t)(t) * 512 + loff];   \
  set[3] = *(const s16x8*)&pb3[(size_t)(t) * 512 + loff];
#define MFMA16(aset, bset)                                                                \
  __builtin_amdgcn_s_setprio(1);                                                          \
  _Pragma("unroll") for (int m = 0; m < 4; m++) _Pragma("unroll") for (int n = 0; n < 4;  \
                                                                       n++) acc[m][n] =  \
      __builtin_amdgcn_mfma_f32_16x16x32_bf16(aset[m], bset[n], acc[m][n], 0, 0, 0);      \
  __builtin_amdgcn_s_setprio(0);

  f32x4 acc[4][4] = {};
  s16x8 aA[4], bA[4], aB[4], bB[4];
  LDA(aA, 0); LDB(bA, 0);
  for (int t = 0; t < 32; t += 2) {
    const int t1 = t + 1;
    LDA(aB, t1); LDB(bB, t1);
    MFMA16(aA, bA);
    const int t2 = (t + 2 < 32) ? t + 2 : 31;
    LDA(aA, t2); LDB(bA, t2);
    MFMA16(aB, bB);
  }
#undef LDA
#undef LDB
#undef MFMA16

#pragma unroll
  for (int m = 0; m < 4; m++)
#pragma unroll
    for (int n = 0; n < 4; n++)
#pragma unroll
      for (int r = 0; r < 4; r++) {
        int row = m0 + wr * 64 + m * 16 + lq * 4 + r;
        int col = n0 + wc * 64 + n * 16 + l15;
        C[(size_t)row * 1024 + col] = acc[m][n][r] + bias[col];
      }
}

// ---------------- Flash attention (causal), swapped-operand, zero-LDS ----------------
// Q pre-scaled by c => QK MFMA emits S*c directly; P = exp2(S*c), no fma, no M0.
// Wave-uniform pairing: wave owns chunks (63-ci, ci). P-pack via cvt_pk + permlane32_swap.
// Rowsum via MFMA-ones (element 0). Output stored in A-frag layout (attf).
__global__ __launch_bounds__(256, 3) void attn_kernel(const unsigned short* __restrict__ qbuf,
                                                      const unsigned short* __restrict__ kf,
                                                      const unsigned short* __restrict__ vf,
                                                      unsigned short* __restrict__ attf) {
  const int tid = threadIdx.x, l = tid & 63, w = tid >> 6;
  const int q32 = l & 31, hi = l >> 5;
  // XCD-bijective swizzle: 512 blocks, 64 consecutive lbids per XCD (K/V 4MB = L2).
  const int lbid = (blockIdx.x & 7) * 64 + (blockIdx.x >> 3);
  const int pig = lbid & 7;
  const int h = (lbid >> 3) & 15, b = lbid >> 7;
  const int ci = pig * 4 + w;  // wave-task id 0..31
  const size_t rowbase = (size_t)b * 2048;
  const unsigned short* kbase = kf + (size_t)((b * 16 + h) * 64) * 2048;
  const unsigned short* vbase = vf + (size_t)((b * 16 + h) * 64) * 2048;
  const int loff = l * 8;
  const s16x8 vones = {16256, 16256, 16256, 16256, 16256, 16256, 16256, 16256};

  for (int half = 0; half < 2; half++) {
    const int cc = half ? ci : 63 - ci;  // 32-row chunk, 0..63
    const int qw0 = cc * 32;
    const int tl = cc;  // diagonal 32-key tile

    s16x8 qf[4];
#pragma unroll
    for (int ds = 0; ds < 4; ds++)
      qf[ds] = *(const s16x8*)&qbuf[(rowbase + qw0 + q32) * 1024 + h * 64 + ds * 16 + hi * 8];

    f32x16 oacc0 = {}, oacc1 = {}, lsum = {};

    s16x8 bk[4], bv[4];
#pragma unroll
    for (int f = 0; f < 4; f++) {
      bk[f] = *(const s16x8*)&kbase[f * 512 + loff];
      bv[f] = *(const s16x8*)&vbase[f * 512 + loff];
    }

    for (int t = 0; t <= tl; ++t) {
      // ---- S*c = K·(Q*c)^T ----
      f32x16 st = {};
      __builtin_amdgcn_s_setprio(1);
#pragma unroll
      for (int ds = 0; ds < 4; ds++)
        st = __builtin_amdgcn_mfma_f32_32x32x16_bf16(bk[ds], qf[ds], st, 0, 0, 0);
      __builtin_amdgcn_s_setprio(0);
      {
        const int tn = (t < tl) ? t + 1 : 0;
        const unsigned short* kt = kbase + (size_t)tn * 2048;
#pragma unroll
        for (int f = 0; f < 4; f++) bk[f] = *(const s16x8*)&kt[f * 512 + loff];
      }
      // ---- causal mask (diagonal tile only) ----
      if (t == tl) {
#pragma unroll
        for (int reg = 0; reg < 16; reg++) {
          const int creg = (reg & 3) + 8 * (reg >> 2);
          st[reg] = (creg + 4 * hi <= q32) ? st[reg] : -1e30f;
        }
      }
      // ---- P = exp2(S*c); masked -> 0. ----
#pragma unroll
      for (int reg = 0; reg < 16; reg++) st[reg] = exp2f(st[reg]);
      // ---- pack P -> B-operand frags: cvt_pk + permlane32_swap (T12) ----
      s16x8 pa[2];
#pragma unroll
      for (int ks = 0; ks < 2; ks++) {
        const int bq = ks * 8;
        unsigned a0 = cvtpk(st[bq + 0], st[bq + 1]);
        unsigned a1 = cvtpk(st[bq + 2], st[bq + 3]);
        unsigned b0 = cvtpk(st[bq + 4], st[bq + 5]);
        unsigned b1 = cvtpk(st[bq + 6], st[bq + 7]);
        u32x2 s0 = __builtin_amdgcn_permlane32_swap(a0, b0, false, false);
        u32x2 s1 = __builtin_amdgcn_permlane32_swap(a1, b1, false, false);
        pa[ks] = __builtin_bit_cast(s16x8, (u32x4){s0[0], s1[0], s0[1], s1[1]});
      }
      // ---- O^T += V^T·P ; rowsum += ones·P (element 0 tracked) ----
      __builtin_amdgcn_s_setprio(1);
#pragma unroll
      for (int ks = 0; ks < 2; ks++) {
        oacc0 = __builtin_amdgcn_mfma_f32_32x32x16_bf16(bv[0 * 2 + ks], pa[ks], oacc0, 0, 0, 0);
        oacc1 = __builtin_amdgcn_mfma_f32_32x32x16_bf16(bv[1 * 2 + ks], pa[ks], oacc1, 0, 0, 0);
        lsum = __builtin_amdgcn_mfma_f32_32x32x16_bf16(vones, pa[ks], lsum, 0, 0, 0);
      }
      __builtin_amdgcn_s_setprio(0);
      {
        const int tn = (t < tl) ? t + 1 : 0;
        const unsigned short* vtp = vbase + (size_t)tn * 2048;
#pragma unroll
        for (int f = 0; f < 4; f++) bv[f] = *(const s16x8*)&vtp[f * 512 + loff];
      }
    }

    // ---- normalize + store directly in A-frag layout ----
    // attf[((mb*32+kt)*64+lane)*8+j]: mb=R>>4, kt=2h+dh, lane=(q32&15)+16rg, j=4hi+r
    const float rinv = 1.0f / lsum[0];
    const size_t mb = ((rowbase + qw0) >> 4) + (q32 >> 4);
    const int ld0 = q32 & 15;
#pragma unroll
    for (int rg = 0; rg < 4; rg++) {
      u16x4 o0, o1;
#pragma unroll
      for (int r = 0; r < 4; r++) {
        o0[r] = f2b(oacc0[rg * 4 + r] * rinv);
        o1[r] = f2b(oacc1[rg * 4 + r] * rinv);
      }
      *(u16x4*)&attf[((mb * 32 + 2 * h + 0) * 64 + ld0 + 16 * rg) * 8 + 4 * hi] = o0;
      *(u16x4*)&attf[((mb * 32 + 2 * h + 1) * 64 + ld0 + 16 * rg) * 8 + 4 * hi] = o1;
    }
  }
}

extern "C" void kernel_launch(void* const* d_in, const int* in_sizes, int n_in,
                              void* d_out, int out_size, void* d_ws, size_t ws_size,
                              hipStream_t stream) {
  const float* x = (const float*)d_in[0];
  const float* wqkv = (const float*)d_in[1];
  const float* wproj = (const float*)d_in[2];
  const float* bproj = (const float*)d_in[3];
  float* out = (float*)d_out;

  unsigned short* apack = (unsigned short*)d_ws;         // 8192*1024
  unsigned short* bpack = apack + (size_t)8192 * 1024;   // 3072*1024
  unsigned short* wprojp = bpack + (size_t)3072 * 1024;  // 1024*1024
  unsigned short* qbuf = wprojp + (size_t)1024 * 1024;   // 8192*1024
  unsigned short* kfb = qbuf + (size_t)8192 * 1024;      // 64*64*2048
  unsigned short* vfb = kfb + (size_t)64 * 64 * 2048;    // 64*64*2048
  unsigned short* attf = vfb + (size_t)64 * 64 * 2048;   // 8192*1024 (A-frag layout)

  pack3_kernel<<<6144, 256, 0, stream>>>(x, wqkv, wproj, apack, bpack, wprojp);

  gemm_fd<<<1536, 256, 0, stream>>>(apack, bpack, qbuf, kfb, vfb);

  attn_kernel<<<512, 256, 0, stream>>>(qbuf, kfb, vfb, attf);

  gemm_pd<<<512, 256, 0, stream>>>(attf, wprojp, bproj, out);
}

// Round 30
// 160.508 us; speedup vs baseline: 1.0046x; 1.0046x over previous
//
#include <hip/hip_runtime.h>
#include <stdint.h>

// B=4, T=2048, C=1024, H=16, HD=64
// apack/bpack/wprojp: fragment-linear bf16 ([rb16][kt32][lane][8])
// qbuf: [B*T][1024] bf16, PRE-SCALED by c=0.125*log2(e) ; kf/vf: 32x32x16 A-frag tiles
// attf: A-frag layout

typedef float f32x4 __attribute__((ext_vector_type(4)));
typedef float f32x16 __attribute__((ext_vector_type(16)));
typedef short s16x8 __attribute__((ext_vector_type(8)));
typedef unsigned short u16x4 __attribute__((ext_vector_type(4)));
typedef unsigned int u32x4 __attribute__((ext_vector_type(4)));
typedef unsigned int u32x2 __attribute__((ext_vector_type(2)));

__device__ __forceinline__ unsigned short f2b(float f) {
  unsigned u = __builtin_bit_cast(unsigned, f);
  u += 0x7fffu + ((u >> 16) & 1u);
  return (unsigned short)(u >> 16);
}

__device__ __forceinline__ unsigned cvtpk(float lo, float hi) {
  unsigned r;
  asm("v_cvt_pk_bf16_f32 %0, %1, %2" : "=v"(r) : "v"(lo), "v"(hi));
  return r;
}

// ---------------- fused fp32 [R][1024] -> fragment-linear bf16 pack (x, wqkv, wproj) ----------------
// out[rb][kt][lane][8] = in[rb*16 + (lane&15)][kt*32 + (lane>>4)*8 + j]
// One launch, three block ranges: [0,4096) x -> apack; [4096,5632) wqkv -> bpack;
// [5632,6144) wproj -> wprojp. Wave-uniform branch, identical per-element code.
__global__ __launch_bounds__(256) void pack3_kernel(const float* __restrict__ x,
                                                    const float* __restrict__ wqkv,
                                                    const float* __restrict__ wproj,
                                                    unsigned short* __restrict__ apack,
                                                    unsigned short* __restrict__ bpack,
                                                    unsigned short* __restrict__ wprojp) {
  const float* in;
  unsigned short* out;
  int i;
  const int blk = blockIdx.x;
  if (blk < 4096) {
    in = x; out = apack; i = blk * 256 + threadIdx.x;
  } else if (blk < 4096 + 1536) {
    in = wqkv; out = bpack; i = (blk - 4096) * 256 + threadIdx.x;
  } else {
    in = wproj; out = wprojp; i = (blk - 4096 - 1536) * 256 + threadIdx.x;
  }
  int lane = i & 63, kt = (i >> 6) & 31, rb = i >> 11;
  int row = rb * 16 + (lane & 15);
  int col = kt * 32 + ((lane >> 4) << 3);
  const float4* p = reinterpret_cast<const float4*>(in + (size_t)row * 1024 + col);
  float4 v0 = p[0], v1 = p[1];
  s16x8 o;
  o[0] = (short)f2b(v0.x); o[1] = (short)f2b(v0.y);
  o[2] = (short)f2b(v0.z); o[3] = (short)f2b(v0.w);
  o[4] = (short)f2b(v1.x); o[5] = (short)f2b(v1.y);
  o[6] = (short)f2b(v1.z); o[7] = (short)f2b(v1.w);
  *(s16x8*)&out[(size_t)i * 8] = o;
}

// ---------------- QKV GEMM: fragment-direct, zero-LDS, barrier-free ----------------
// Full A/B ping-pong register double-buffer (validated optimum: 70 us, 733 TF).
// Q epilogue pre-scales by c = 0.125*log2(e) so attn's QK MFMA emits S*c directly.
__global__ __launch_bounds__(256) void gemm_fd(const unsigned short* __restrict__ ap,
                                               const unsigned short* __restrict__ bp,
                                               unsigned short* __restrict__ qbuf,
                                               unsigned short* __restrict__ kf,
                                               unsigned short* __restrict__ vf) {
  const int tid = threadIdx.x;
  const int l = tid & 63, w = tid >> 6;
  const int l15 = l & 15, lq = l >> 4;
  const int wr = w >> 1, wc = w & 1;
  const int xcd = blockIdx.x & 7;
  const int idx = blockIdx.x >> 3;
  const int m0 = (xcd * 8 + (idx & 7)) * 128;
  const int n0 = (idx >> 3) * 128;
  const int mb0 = (m0 >> 4) + wr * 4;
  const int nb0 = (n0 >> 4) + wc * 4;
  const int loff = l * 8;

  const unsigned short* pa0 = ap + ((size_t)(mb0 + 0) * 32) * 512 + loff;
  const unsigned short* pa1 = ap + ((size_t)(mb0 + 1) * 32) * 512 + loff;
  const unsigned short* pa2 = ap + ((size_t)(mb0 + 2) * 32) * 512 + loff;
  const unsigned short* pa3 = ap + ((size_t)(mb0 + 3) * 32) * 512 + loff;
  const unsigned short* pb0 = bp + ((size_t)(nb0 + 0) * 32) * 512 + loff;
  const unsigned short* pb1 = bp + ((size_t)(nb0 + 1) * 32) * 512 + loff;
  const unsigned short* pb2 = bp + ((size_t)(nb0 + 2) * 32) * 512 + loff;
  const unsigned short* pb3 = bp + ((size_t)(nb0 + 3) * 32) * 512 + loff;

#define LDA(set, t)                                \
  set[0] = *(const s16x8*)&pa0[(size_t)(t) * 512]; \
  set[1] = *(const s16x8*)&pa1[(size_t)(t) * 512]; \
  set[2] = *(const s16x8*)&pa2[(size_t)(t) * 512]; \
  set[3] = *(const s16x8*)&pa3[(size_t)(t) * 512];
#define LDB(set, t)                                \
  set[0] = *(const s16x8*)&pb0[(size_t)(t) * 512]; \
  set[1] = *(const s16x8*)&pb1[(size_t)(t) * 512]; \
  set[2] = *(const s16x8*)&pb2[(size_t)(t) * 512]; \
  set[3] = *(const s16x8*)&pb3[(size_t)(t) * 512];
#define MFMA16(aset, bset)                                                                \
  __builtin_amdgcn_s_setprio(1);                                                          \
  _Pragma("unroll") for (int m = 0; m < 4; m++) _Pragma("unroll") for (int n = 0; n < 4;  \
                                                                       n++) acc[m][n] =  \
      __builtin_amdgcn_mfma_f32_16x16x32_bf16(aset[m], bset[n], acc[m][n], 0, 0, 0);      \
  __builtin_amdgcn_s_setprio(0);

  f32x4 acc[4][4] = {};
  s16x8 aA[4], bA[4], aB[4], bB[4];
  LDA(aA, 0); LDB(bA, 0);
  for (int t = 0; t < 32; t += 2) {
    const int t1 = t + 1;
    LDA(aB, t1); LDB(bB, t1);
    MFMA16(aA, bA);
    const int t2 = (t + 2 < 32) ? t + 2 : 31;
    LDA(aA, t2); LDB(bA, t2);
    MFMA16(aB, bB);
  }
#undef LDA
#undef LDB

  if (n0 < 1024) {
    const float c = 0.18033688011112042f;  // fold softmax scale into Q
#pragma unroll
    for (int m = 0; m < 4; m++)
#pragma unroll
      for (int n = 0; n < 4; n++)
#pragma unroll
        for (int r = 0; r < 4; r++) {
          int row = m0 + wr * 64 + m * 16 + lq * 4 + r;
          int col = n0 + wc * 64 + n * 16 + l15;
          qbuf[(size_t)row * 1024 + col] = f2b(acc[m][n][r] * c);
        }
  } else if (n0 < 2048) {
#pragma unroll
    for (int m = 0; m < 4; m++)
#pragma unroll
      for (int n = 0; n < 4; n++)
#pragma unroll
        for (int r = 0; r < 4; r++) {
          int key = m0 + wr * 64 + m * 16 + lq * 4 + r;
          int col = n0 - 1024 + wc * 64 + n * 16 + l15;  // h*64+d
          int hh = col >> 6, d = col & 63;
          int bb = key >> 11, k2 = key & 2047, t = k2 >> 5, ki = k2 & 31;
          int ds = d >> 4, hid = (d >> 3) & 1;
          kf[((size_t)((bb * 16 + hh) * 64 + t)) * 2048 + ds * 512 + (hid * 32 + ki) * 8 +
             (d & 7)] = f2b(acc[m][n][r]);
        }
  } else {
#pragma unroll
    for (int m = 0; m < 4; m++)
#pragma unroll
      for (int n = 0; n < 4; n++) {
        int key0 = m0 + wr * 64 + m * 16 + lq * 4;
        int col = n0 - 2048 + wc * 64 + n * 16 + l15;  // h*64+d
        int hh = col >> 6, d = col & 63;
        int bb = key0 >> 11, k2 = key0 & 2047, t = k2 >> 5, ki0 = k2 & 31;
        int ks = ki0 >> 4, hik = (ki0 >> 3) & 1, j0 = ki0 & 7;
        int dh = d >> 5;
        u16x4 o;
#pragma unroll
        for (int r = 0; r < 4; r++) o[r] = f2b(acc[m][n][r]);
        *(u16x4*)&vf[((size_t)((bb * 16 + hh) * 64 + t)) * 2048 + (dh * 2 + ks) * 512 +
                     (hik * 32 + (d & 31)) * 8 + j0] = o;
      }
  }
}

// ---------------- proj GEMM: fragment-direct, zero-LDS, barrier-free, f32+bias ----------------
__global__ __launch_bounds__(256) void gemm_pd(const unsigned short* __restrict__ ap,
                                               const unsigned short* __restrict__ bp,
                                               const float* __restrict__ bias,
                                               float* __restrict__ C) {
  const int tid = threadIdx.x;
  const int l = tid & 63, w = tid >> 6;
  const int l15 = l & 15, lq = l >> 4;
  const int wr = w >> 1, wc = w & 1;
  const int xcd = blockIdx.x & 7;
  const int idx = blockIdx.x >> 3;
  const int m0 = (xcd * 8 + (idx & 7)) * 128;
  const int n0 = (idx >> 3) * 128;
  const int mb0 = (m0 >> 4) + wr * 4;
  const int nb0 = (n0 >> 4) + wc * 4;
  const int loff = l * 8;

  const unsigned short* pa0 = ap + ((size_t)(mb0 + 0) * 32) * 512 + loff;
  const unsigned short* pa1 = ap + ((size_t)(mb0 + 1) * 32) * 512 + loff;
  const unsigned short* pa2 = ap + ((size_t)(mb0 + 2) * 32) * 512 + loff;
  const unsigned short* pa3 = ap + ((size_t)(mb0 + 3) * 32) * 512 + loff;
  const unsigned short* pb0 = bp + ((size_t)(nb0 + 0) * 32) * 512 + loff;
  const unsigned short* pb1 = bp + ((size_t)(nb0 + 1) * 32) * 512 + loff;
  const unsigned short* pb2 = bp + ((size_t)(nb0 + 2) * 32) * 512 + loff;
  const unsigned short* pb3 = bp + ((size_t)(nb0 + 3) * 32) * 512 + loff;

#define LDA(set, t)                                \
  set[0] = *(const s16x8*)&pa0[(size_t)(t) * 512]; \
  set[1] = *(const s16x8*)&pa1[(size_t)(t) * 512]; \
  set[2] = *(const s16x8*)&pa2[(size_t)(t) * 512]; \
  set[3] = *(const s16x8*)&pa3[(size_t)(t) * 512];
#define LDB(set, t)                                \
  set[0] = *(const s16x8*)&pb0[(size_t)(t) * 512]; \
  set[1] = *(const s16x8*)&pb1[(size_t)(t) * 512]; \
  set[2] = *(const s16x8*)&pb2[(size_t)(t) * 512]; \
  set[3] = *(const s16x8*)&pb3[(size_t)(t) * 512];
#define MFMA16(aset, bset)                                                                \
  __builtin_amdgcn_s_setprio(1);                                                          \
  _Pragma("unroll") for (int m = 0; m < 4; m++) _Pragma("unroll") for (int n = 0; n < 4;  \
                                                                       n++) acc[m][n] =  \
      __builtin_amdgcn_mfma_f32_16x16x32_bf16(aset[m], bset[n], acc[m][n], 0, 0, 0);      \
  __builtin_amdgcn_s_setprio(0);

  f32x4 acc[4][4] = {};
  s16x8 aA[4], bA[4], aB[4], bB[4];
  LDA(aA, 0); LDB(bA, 0);
  for (int t = 0; t < 32; t += 2) {
    const int t1 = t + 1;
    LDA(aB, t1); LDB(bB, t1);
    MFMA16(aA, bA);
    const int t2 = (t + 2 < 32) ? t + 2 : 31;
    LDA(aA, t2); LDB(bA, t2);
    MFMA16(aB, bB);
  }
#undef LDA
#undef LDB
#undef MFMA16

#pragma unroll
  for (int m = 0; m < 4; m++)
#pragma unroll
    for (int n = 0; n < 4; n++)
#pragma unroll
      for (int r = 0; r < 4; r++) {
        int row = m0 + wr * 64 + m * 16 + lq * 4 + r;
        int col = n0 + wc * 64 + n * 16 + l15;
        C[(size_t)row * 1024 + col] = acc[m][n][r] + bias[col];
      }
}

// ---------------- Flash attention (causal), swapped-operand, zero-LDS ----------------
// Q pre-scaled by c => QK MFMA emits S*c directly; P = exp2(S*c), no fma, no M0.
// Wave-uniform pairing: wave owns chunks (63-ci, ci). P-pack via cvt_pk + permlane32_swap.
// Rowsum via MFMA-ones (element 0). Output stored in A-frag layout (attf).
__global__ __launch_bounds__(256, 3) void attn_kernel(const unsigned short* __restrict__ qbuf,
                                                      const unsigned short* __restrict__ kf,
                                                      const unsigned short* __restrict__ vf,
                                                      unsigned short* __restrict__ attf) {
  const int tid = threadIdx.x, l = tid & 63, w = tid >> 6;
  const int q32 = l & 31, hi = l >> 5;
  // XCD-bijective swizzle: 512 blocks, 64 consecutive lbids per XCD (K/V 4MB = L2).
  const int lbid = (blockIdx.x & 7) * 64 + (blockIdx.x >> 3);
  const int pig = lbid & 7;
  const int h = (lbid >> 3) & 15, b = lbid >> 7;
  const int ci = pig * 4 + w;  // wave-task id 0..31
  const size_t rowbase = (size_t)b * 2048;
  const unsigned short* kbase = kf + (size_t)((b * 16 + h) * 64) * 2048;
  const unsigned short* vbase = vf + (size_t)((b * 16 + h) * 64) * 2048;
  const int loff = l * 8;
  const s16x8 vones = {16256, 16256, 16256, 16256, 16256, 16256, 16256, 16256};

  for (int half = 0; half < 2; half++) {
    const int cc = half ? ci : 63 - ci;  // 32-row chunk, 0..63
    const int qw0 = cc * 32;
    const int tl = cc;  // diagonal 32-key tile

    s16x8 qf[4];
#pragma unroll
    for (int ds = 0; ds < 4; ds++)
      qf[ds] = *(const s16x8*)&qbuf[(rowbase + qw0 + q32) * 1024 + h * 64 + ds * 16 + hi * 8];

    f32x16 oacc0 = {}, oacc1 = {}, lsum = {};

    s16x8 bk[4], bv[4];
#pragma unroll
    for (int f = 0; f < 4; f++) {
      bk[f] = *(const s16x8*)&kbase[f * 512 + loff];
      bv[f] = *(const s16x8*)&vbase[f * 512 + loff];
    }

    for (int t = 0; t <= tl; ++t) {
      // ---- S*c = K·(Q*c)^T ----
      f32x16 st = {};
      __builtin_amdgcn_s_setprio(1);
#pragma unroll
      for (int ds = 0; ds < 4; ds++)
        st = __builtin_amdgcn_mfma_f32_32x32x16_bf16(bk[ds], qf[ds], st, 0, 0, 0);
      __builtin_amdgcn_s_setprio(0);
      {
        const int tn = (t < tl) ? t + 1 : 0;
        const unsigned short* kt = kbase + (size_t)tn * 2048;
#pragma unroll
        for (int f = 0; f < 4; f++) bk[f] = *(const s16x8*)&kt[f * 512 + loff];
      }
      // ---- causal mask (diagonal tile only) ----
      if (t == tl) {
#pragma unroll
        for (int reg = 0; reg < 16; reg++) {
          const int creg = (reg & 3) + 8 * (reg >> 2);
          st[reg] = (creg + 4 * hi <= q32) ? st[reg] : -1e30f;
        }
      }
      // ---- P = exp2(S*c); masked -> 0. ----
#pragma unroll
      for (int reg = 0; reg < 16; reg++) st[reg] = exp2f(st[reg]);
      // ---- pack P -> B-operand frags: cvt_pk + permlane32_swap (T12) ----
      s16x8 pa[2];
#pragma unroll
      for (int ks = 0; ks < 2; ks++) {
        const int bq = ks * 8;
        unsigned a0 = cvtpk(st[bq + 0], st[bq + 1]);
        unsigned a1 = cvtpk(st[bq + 2], st[bq + 3]);
        unsigned b0 = cvtpk(st[bq + 4], st[bq + 5]);
        unsigned b1 = cvtpk(st[bq + 6], st[bq + 7]);
        u32x2 s0 = __builtin_amdgcn_permlane32_swap(a0, b0, false, false);
        u32x2 s1 = __builtin_amdgcn_permlane32_swap(a1, b1, false, false);
        pa[ks] = __builtin_bit_cast(s16x8, (u32x4){s0[0], s1[0], s0[1], s1[1]});
      }
      // ---- O^T += V^T·P ; rowsum += ones·P (element 0 tracked) ----
      __builtin_amdgcn_s_setprio(1);
#pragma unroll
      for (int ks = 0; ks < 2; ks++) {
        oacc0 = __builtin_amdgcn_mfma_f32_32x32x16_bf16(bv[0 * 2 + ks], pa[ks], oacc0, 0, 0, 0);
        oacc1 = __builtin_amdgcn_mfma_f32_32x32x16_bf16(bv[1 * 2 + ks], pa[ks], oacc1, 0, 0, 0);
        lsum = __builtin_amdgcn_mfma_f32_32x32x16_bf16(vones, pa[ks], lsum, 0, 0, 0);
      }
      __builtin_amdgcn_s_setprio(0);
      {
        const int tn = (t < tl) ? t + 1 : 0;
        const unsigned short* vtp = vbase + (size_t)tn * 2048;
#pragma unroll
        for (int f = 0; f < 4; f++) bv[f] = *(const s16x8*)&vtp[f * 512 + loff];
      }
    }

    // ---- normalize + store directly in A-frag layout ----
    // attf[((mb*32+kt)*64+lane)*8+j]: mb=R>>4, kt=2h+dh, lane=(q32&15)+16rg, j=4hi+r
    const float rinv = 1.0f / lsum[0];
    const size_t mb = ((rowbase + qw0) >> 4) + (q32 >> 4);
    const int ld0 = q32 & 15;
#pragma unroll
    for (int rg = 0; rg < 4; rg++) {
      u16x4 o0, o1;
#pragma unroll
      for (int r = 0; r < 4; r++) {
        o0[r] = f2b(oacc0[rg * 4 + r] * rinv);
        o1[r] = f2b(oacc1[rg * 4 + r] * rinv);
      }
      *(u16x4*)&attf[((mb * 32 + 2 * h + 0) * 64 + ld0 + 16 * rg) * 8 + 4 * hi] = o0;
      *(u16x4*)&attf[((mb * 32 + 2 * h + 1) * 64 + ld0 + 16 * rg) * 8 + 4 * hi] = o1;
    }
  }
}

extern "C" void kernel_launch(void* const* d_in, const int* in_sizes, int n_in,
                              void* d_out, int out_size, void* d_ws, size_t ws_size,
                              hipStream_t stream) {
  const float* x = (const float*)d_in[0];
  const float* wqkv = (const float*)d_in[1];
  const float* wproj = (const float*)d_in[2];
  const float* bproj = (const float*)d_in[3];
  float* out = (float*)d_out;

  unsigned short* apack = (unsigned short*)d_ws;         // 8192*1024
  unsigned short* bpack = apack + (size_t)8192 * 1024;   // 3072*1024
  unsigned short* wprojp = bpack + (size_t)3072 * 1024;  // 1024*1024
  unsigned short* qbuf = wprojp + (size_t)1024 * 1024;   // 8192*1024
  unsigned short* kfb = qbuf + (size_t)8192 * 1024;      // 64*64*2048
  unsigned short* vfb = kfb + (size_t)64 * 64 * 2048;    // 64*64*2048
  unsigned short* attf = vfb + (size_t)64 * 64 * 2048;   // 8192*1024 (A-frag layout)

  pack3_kernel<<<6144, 256, 0, stream>>>(x, wqkv, wproj, apack, bpack, wprojp);

  gemm_fd<<<1536, 256, 0, stream>>>(apack, bpack, qbuf, kfb, vfb);

  attn_kernel<<<512, 256, 0, stream>>>(qbuf, kfb, vfb, attf);

  gemm_pd<<<512, 256, 0, stream>>>(attf, wprojp, bproj, out);
}

// Round 31
// 160.496 us; speedup vs baseline: 1.0047x; 1.0001x over previous
//
#include <hip/hip_runtime.h>
#include <stdint.h>

// B=4, T=2048, C=1024, H=16, HD=64
// apack/bpack/wprojp: fragment-linear bf16 ([rb16][kt32][lane][8])
// qbuf: [B*T][1024] bf16, PRE-SCALED by c=0.125*log2(e) ; kf/vf: 32x32x16 A-frag tiles
// attf: A-frag layout

typedef float f32x4 __attribute__((ext_vector_type(4)));
typedef float f32x16 __attribute__((ext_vector_type(16)));
typedef short s16x8 __attribute__((ext_vector_type(8)));
typedef unsigned short u16x4 __attribute__((ext_vector_type(4)));
typedef unsigned int u32x4 __attribute__((ext_vector_type(4)));
typedef unsigned int u32x2 __attribute__((ext_vector_type(2)));

__device__ __forceinline__ unsigned short f2b(float f) {
  unsigned u = __builtin_bit_cast(unsigned, f);
  u += 0x7fffu + ((u >> 16) & 1u);
  return (unsigned short)(u >> 16);
}

__device__ __forceinline__ unsigned cvtpk(float lo, float hi) {
  unsigned r;
  asm("v_cvt_pk_bf16_f32 %0, %1, %2" : "=v"(r) : "v"(lo), "v"(hi));
  return r;
}

// ---------------- fused fp32 [R][1024] -> fragment-linear bf16 pack (x, wqkv, wproj) ----------------
// out[rb][kt][lane][8] = in[rb*16 + (lane&15)][kt*32 + (lane>>4)*8 + j]
// One launch, three block ranges: [0,4096) x -> apack; [4096,5632) wqkv -> bpack;
// [5632,6144) wproj -> wprojp. Wave-uniform branch, identical per-element code.
__global__ __launch_bounds__(256) void pack3_kernel(const float* __restrict__ x,
                                                    const float* __restrict__ wqkv,
                                                    const float* __restrict__ wproj,
                                                    unsigned short* __restrict__ apack,
                                                    unsigned short* __restrict__ bpack,
                                                    unsigned short* __restrict__ wprojp) {
  const float* in;
  unsigned short* out;
  int i;
  const int blk = blockIdx.x;
  if (blk < 4096) {
    in = x; out = apack; i = blk * 256 + threadIdx.x;
  } else if (blk < 4096 + 1536) {
    in = wqkv; out = bpack; i = (blk - 4096) * 256 + threadIdx.x;
  } else {
    in = wproj; out = wprojp; i = (blk - 4096 - 1536) * 256 + threadIdx.x;
  }
  int lane = i & 63, kt = (i >> 6) & 31, rb = i >> 11;
  int row = rb * 16 + (lane & 15);
  int col = kt * 32 + ((lane >> 4) << 3);
  const float4* p = reinterpret_cast<const float4*>(in + (size_t)row * 1024 + col);
  float4 v0 = p[0], v1 = p[1];
  s16x8 o;
  o[0] = (short)f2b(v0.x); o[1] = (short)f2b(v0.y);
  o[2] = (short)f2b(v0.z); o[3] = (short)f2b(v0.w);
  o[4] = (short)f2b(v1.x); o[5] = (short)f2b(v1.y);
  o[6] = (short)f2b(v1.z); o[7] = (short)f2b(v1.w);
  *(s16x8*)&out[(size_t)i * 8] = o;
}

// ---------------- QKV GEMM: fragment-direct, zero-LDS, barrier-free ----------------
// Full A/B ping-pong register double-buffer (validated optimum: 70 us, 733 TF).
// Q epilogue pre-scales by c = 0.125*log2(e) so attn's QK MFMA emits S*c directly.
__global__ __launch_bounds__(256) void gemm_fd(const unsigned short* __restrict__ ap,
                                               const unsigned short* __restrict__ bp,
                                               unsigned short* __restrict__ qbuf,
                                               unsigned short* __restrict__ kf,
                                               unsigned short* __restrict__ vf) {
  const int tid = threadIdx.x;
  const int l = tid & 63, w = tid >> 6;
  const int l15 = l & 15, lq = l >> 4;
  const int wr = w >> 1, wc = w & 1;
  const int xcd = blockIdx.x & 7;
  const int idx = blockIdx.x >> 3;
  const int m0 = (xcd * 8 + (idx & 7)) * 128;
  const int n0 = (idx >> 3) * 128;
  const int mb0 = (m0 >> 4) + wr * 4;
  const int nb0 = (n0 >> 4) + wc * 4;
  const int loff = l * 8;

  const unsigned short* pa0 = ap + ((size_t)(mb0 + 0) * 32) * 512 + loff;
  const unsigned short* pa1 = ap + ((size_t)(mb0 + 1) * 32) * 512 + loff;
  const unsigned short* pa2 = ap + ((size_t)(mb0 + 2) * 32) * 512 + loff;
  const unsigned short* pa3 = ap + ((size_t)(mb0 + 3) * 32) * 512 + loff;
  const unsigned short* pb0 = bp + ((size_t)(nb0 + 0) * 32) * 512 + loff;
  const unsigned short* pb1 = bp + ((size_t)(nb0 + 1) * 32) * 512 + loff;
  const unsigned short* pb2 = bp + ((size_t)(nb0 + 2) * 32) * 512 + loff;
  const unsigned short* pb3 = bp + ((size_t)(nb0 + 3) * 32) * 512 + loff;

#define LDA(set, t)                                \
  set[0] = *(const s16x8*)&pa0[(size_t)(t) * 512]; \
  set[1] = *(const s16x8*)&pa1[(size_t)(t) * 512]; \
  set[2] = *(const s16x8*)&pa2[(size_t)(t) * 512]; \
  set[3] = *(const s16x8*)&pa3[(size_t)(t) * 512];
#define LDB(set, t)                                \
  set[0] = *(const s16x8*)&pb0[(size_t)(t) * 512]; \
  set[1] = *(const s16x8*)&pb1[(size_t)(t) * 512]; \
  set[2] = *(const s16x8*)&pb2[(size_t)(t) * 512]; \
  set[3] = *(const s16x8*)&pb3[(size_t)(t) * 512];
#define MFMA16(aset, bset)                                                                \
  __builtin_amdgcn_s_setprio(1);                                                          \
  _Pragma("unroll") for (int m = 0; m < 4; m++) _Pragma("unroll") for (int n = 0; n < 4;  \
                                                                       n++) acc[m][n] =  \
      __builtin_amdgcn_mfma_f32_16x16x32_bf16(aset[m], bset[n], acc[m][n], 0, 0, 0);      \
  __builtin_amdgcn_s_setprio(0);

  f32x4 acc[4][4] = {};
  s16x8 aA[4], bA[4], aB[4], bB[4];
  LDA(aA, 0); LDB(bA, 0);
  for (int t = 0; t < 32; t += 2) {
    const int t1 = t + 1;
    LDA(aB, t1); LDB(bB, t1);
    MFMA16(aA, bA);
    const int t2 = (t + 2 < 32) ? t + 2 : 31;
    LDA(aA, t2); LDB(bA, t2);
    MFMA16(aB, bB);
  }
#undef LDA
#undef LDB

  if (n0 < 1024) {
    const float c = 0.18033688011112042f;  // fold softmax scale into Q
#pragma unroll
    for (int m = 0; m < 4; m++)
#pragma unroll
      for (int n = 0; n < 4; n++)
#pragma unroll
        for (int r = 0; r < 4; r++) {
          int row = m0 + wr * 64 + m * 16 + lq * 4 + r;
          int col = n0 + wc * 64 + n * 16 + l15;
          qbuf[(size_t)row * 1024 + col] = f2b(acc[m][n][r] * c);
        }
  } else if (n0 < 2048) {
#pragma unroll
    for (int m = 0; m < 4; m++)
#pragma unroll
      for (int n = 0; n < 4; n++)
#pragma unroll
        for (int r = 0; r < 4; r++) {
          int key = m0 + wr * 64 + m * 16 + lq * 4 + r;
          int col = n0 - 1024 + wc * 64 + n * 16 + l15;  // h*64+d
          int hh = col >> 6, d = col & 63;
          int bb = key >> 11, k2 = key & 2047, t = k2 >> 5, ki = k2 & 31;
          int ds = d >> 4, hid = (d >> 3) & 1;
          kf[((size_t)((bb * 16 + hh) * 64 + t)) * 2048 + ds * 512 + (hid * 32 + ki) * 8 +
             (d & 7)] = f2b(acc[m][n][r]);
        }
  } else {
#pragma unroll
    for (int m = 0; m < 4; m++)
#pragma unroll
      for (int n = 0; n < 4; n++) {
        int key0 = m0 + wr * 64 + m * 16 + lq * 4;
        int col = n0 - 2048 + wc * 64 + n * 16 + l15;  // h*64+d
        int hh = col >> 6, d = col & 63;
        int bb = key0 >> 11, k2 = key0 & 2047, t = k2 >> 5, ki0 = k2 & 31;
        int ks = ki0 >> 4, hik = (ki0 >> 3) & 1, j0 = ki0 & 7;
        int dh = d >> 5;
        u16x4 o;
#pragma unroll
        for (int r = 0; r < 4; r++) o[r] = f2b(acc[m][n][r]);
        *(u16x4*)&vf[((size_t)((bb * 16 + hh) * 64 + t)) * 2048 + (dh * 2 + ks) * 512 +
                     (hik * 32 + (d & 31)) * 8 + j0] = o;
      }
  }
}

// ---------------- proj GEMM: fragment-direct, zero-LDS, barrier-free, f32+bias ----------------
__global__ __launch_bounds__(256) void gemm_pd(const unsigned short* __restrict__ ap,
                                               const unsigned short* __restrict__ bp,
                                               const float* __restrict__ bias,
                                               float* __restrict__ C) {
  const int tid = threadIdx.x;
  const int l = tid & 63, w = tid >> 6;
  const int l15 = l & 15, lq = l >> 4;
  const int wr = w >> 1, wc = w & 1;
  const int xcd = blockIdx.x & 7;
  const int idx = blockIdx.x >> 3;
  const int m0 = (xcd * 8 + (idx & 7)) * 128;
  const int n0 = (idx >> 3) * 128;
  const int mb0 = (m0 >> 4) + wr * 4;
  const int nb0 = (n0 >> 4) + wc * 4;
  const int loff = l * 8;

  const unsigned short* pa0 = ap + ((size_t)(mb0 + 0) * 32) * 512 + loff;
  const unsigned short* pa1 = ap + ((size_t)(mb0 + 1) * 32) * 512 + loff;
  const unsigned short* pa2 = ap + ((size_t)(mb0 + 2) * 32) * 512 + loff;
  const unsigned short* pa3 = ap + ((size_t)(mb0 + 3) * 32) * 512 + loff;
  const unsigned short* pb0 = bp + ((size_t)(nb0 + 0) * 32) * 512 + loff;
  const unsigned short* pb1 = bp + ((size_t)(nb0 + 1) * 32) * 512 + loff;
  const unsigned short* pb2 = bp + ((size_t)(nb0 + 2) * 32) * 512 + loff;
  const unsigned short* pb3 = bp + ((size_t)(nb0 + 3) * 32) * 512 + loff;

#define LDA(set, t)                                \
  set[0] = *(const s16x8*)&pa0[(size_t)(t) * 512]; \
  set[1] = *(const s16x8*)&pa1[(size_t)(t) * 512]; \
  set[2] = *(const s16x8*)&pa2[(size_t)(t) * 512]; \
  set[3] = *(const s16x8*)&pa3[(size_t)(t) * 512];
#define LDB(set, t)                                \
  set[0] = *(const s16x8*)&pb0[(size_t)(t) * 512]; \
  set[1] = *(const s16x8*)&pb1[(size_t)(t) * 512]; \
  set[2] = *(const s16x8*)&pb2[(size_t)(t) * 512]; \
  set[3] = *(const s16x8*)&pb3[(size_t)(t) * 512];
#define MFMA16(aset, bset)                                                                \
  __builtin_amdgcn_s_setprio(1);                                                          \
  _Pragma("unroll") for (int m = 0; m < 4; m++) _Pragma("unroll") for (int n = 0; n < 4;  \
                                                                       n++) acc[m][n] =  \
      __builtin_amdgcn_mfma_f32_16x16x32_bf16(aset[m], bset[n], acc[m][n], 0, 0, 0);      \
  __builtin_amdgcn_s_setprio(0);

  f32x4 acc[4][4] = {};
  s16x8 aA[4], bA[4], aB[4], bB[4];
  LDA(aA, 0); LDB(bA, 0);
  for (int t = 0; t < 32; t += 2) {
    const int t1 = t + 1;
    LDA(aB, t1); LDB(bB, t1);
    MFMA16(aA, bA);
    const int t2 = (t + 2 < 32) ? t + 2 : 31;
    LDA(aA, t2); LDB(bA, t2);
    MFMA16(aB, bB);
  }
#undef LDA
#undef LDB
#undef MFMA16

#pragma unroll
  for (int m = 0; m < 4; m++)
#pragma unroll
    for (int n = 0; n < 4; n++)
#pragma unroll
      for (int r = 0; r < 4; r++) {
        int row = m0 + wr * 64 + m * 16 + lq * 4 + r;
        int col = n0 + wc * 64 + n * 16 + l15;
        C[(size_t)row * 1024 + col] = acc[m][n][r] + bias[col];
      }
}

// ---------------- Flash attention (causal), swapped-operand, zero-LDS ----------------
// Q pre-scaled by c => QK MFMA emits S*c directly; P = exp2(S*c), no fma, no M0.
// Wave-uniform pairing: wave owns chunks (63-ci, ci). P-pack via cvt_pk + permlane32_swap.
// Rowsum via MFMA-ones (element 0). Output stored in A-frag layout (attf).
__global__ __launch_bounds__(256, 3) void attn_kernel(const unsigned short* __restrict__ qbuf,
                                                      const unsigned short* __restrict__ kf,
                                                      const unsigned short* __restrict__ vf,
                                                      unsigned short* __restrict__ attf) {
  const int tid = threadIdx.x, l = tid & 63, w = tid >> 6;
  const int q32 = l & 31, hi = l >> 5;
  // XCD-bijective swizzle: 512 blocks, 64 consecutive lbids per XCD (K/V 4MB = L2).
  const int lbid = (blockIdx.x & 7) * 64 + (blockIdx.x >> 3);
  const int pig = lbid & 7;
  const int h = (lbid >> 3) & 15, b = lbid >> 7;
  const int ci = pig * 4 + w;  // wave-task id 0..31
  const size_t rowbase = (size_t)b * 2048;
  const unsigned short* kbase = kf + (size_t)((b * 16 + h) * 64) * 2048;
  const unsigned short* vbase = vf + (size_t)((b * 16 + h) * 64) * 2048;
  const int loff = l * 8;
  const s16x8 vones = {16256, 16256, 16256, 16256, 16256, 16256, 16256, 16256};

  for (int half = 0; half < 2; half++) {
    const int cc = half ? ci : 63 - ci;  // 32-row chunk, 0..63
    const int qw0 = cc * 32;
    const int tl = cc;  // diagonal 32-key tile

    s16x8 qf[4];
#pragma unroll
    for (int ds = 0; ds < 4; ds++)
      qf[ds] = *(const s16x8*)&qbuf[(rowbase + qw0 + q32) * 1024 + h * 64 + ds * 16 + hi * 8];

    f32x16 oacc0 = {}, oacc1 = {}, lsum = {};

    s16x8 bk[4], bv[4];
#pragma unroll
    for (int f = 0; f < 4; f++) {
      bk[f] = *(const s16x8*)&kbase[f * 512 + loff];
      bv[f] = *(const s16x8*)&vbase[f * 512 + loff];
    }

    for (int t = 0; t <= tl; ++t) {
      // ---- S*c = K·(Q*c)^T ----
      f32x16 st = {};
      __builtin_amdgcn_s_setprio(1);
#pragma unroll
      for (int ds = 0; ds < 4; ds++)
        st = __builtin_amdgcn_mfma_f32_32x32x16_bf16(bk[ds], qf[ds], st, 0, 0, 0);
      __builtin_amdgcn_s_setprio(0);
      {
        const int tn = (t < tl) ? t + 1 : 0;
        const unsigned short* kt = kbase + (size_t)tn * 2048;
#pragma unroll
        for (int f = 0; f < 4; f++) bk[f] = *(const s16x8*)&kt[f * 512 + loff];
      }
      // ---- causal mask (diagonal tile only) ----
      if (t == tl) {
#pragma unroll
        for (int reg = 0; reg < 16; reg++) {
          const int creg = (reg & 3) + 8 * (reg >> 2);
          st[reg] = (creg + 4 * hi <= q32) ? st[reg] : -1e30f;
        }
      }
      // ---- P = exp2(S*c); masked -> 0. ----
#pragma unroll
      for (int reg = 0; reg < 16; reg++) st[reg] = exp2f(st[reg]);
      // ---- pack P -> B-operand frags: cvt_pk + permlane32_swap (T12) ----
      s16x8 pa[2];
#pragma unroll
      for (int ks = 0; ks < 2; ks++) {
        const int bq = ks * 8;
        unsigned a0 = cvtpk(st[bq + 0], st[bq + 1]);
        unsigned a1 = cvtpk(st[bq + 2], st[bq + 3]);
        unsigned b0 = cvtpk(st[bq + 4], st[bq + 5]);
        unsigned b1 = cvtpk(st[bq + 6], st[bq + 7]);
        u32x2 s0 = __builtin_amdgcn_permlane32_swap(a0, b0, false, false);
        u32x2 s1 = __builtin_amdgcn_permlane32_swap(a1, b1, false, false);
        pa[ks] = __builtin_bit_cast(s16x8, (u32x4){s0[0], s1[0], s0[1], s1[1]});
      }
      // ---- O^T += V^T·P ; rowsum += ones·P (element 0 tracked) ----
      __builtin_amdgcn_s_setprio(1);
#pragma unroll
      for (int ks = 0; ks < 2; ks++) {
        oacc0 = __builtin_amdgcn_mfma_f32_32x32x16_bf16(bv[0 * 2 + ks], pa[ks], oacc0, 0, 0, 0);
        oacc1 = __builtin_amdgcn_mfma_f32_32x32x16_bf16(bv[1 * 2 + ks], pa[ks], oacc1, 0, 0, 0);
        lsum = __builtin_amdgcn_mfma_f32_32x32x16_bf16(vones, pa[ks], lsum, 0, 0, 0);
      }
      __builtin_amdgcn_s_setprio(0);
      {
        const int tn = (t < tl) ? t + 1 : 0;
        const unsigned short* vtp = vbase + (size_t)tn * 2048;
#pragma unroll
        for (int f = 0; f < 4; f++) bv[f] = *(const s16x8*)&vtp[f * 512 + loff];
      }
    }

    // ---- normalize + store directly in A-frag layout ----
    // attf[((mb*32+kt)*64+lane)*8+j]: mb=R>>4, kt=2h+dh, lane=(q32&15)+16rg, j=4hi+r
    const float rinv = 1.0f / lsum[0];
    const size_t mb = ((rowbase + qw0) >> 4) + (q32 >> 4);
    const int ld0 = q32 & 15;
#pragma unroll
    for (int rg = 0; rg < 4; rg++) {
      u16x4 o0, o1;
#pragma unroll
      for (int r = 0; r < 4; r++) {
        o0[r] = f2b(oacc0[rg * 4 + r] * rinv);
        o1[r] = f2b(oacc1[rg * 4 + r] * rinv);
      }
      *(u16x4*)&attf[((mb * 32 + 2 * h + 0) * 64 + ld0 + 16 * rg) * 8 + 4 * hi] = o0;
      *(u16x4*)&attf[((mb * 32 + 2 * h + 1) * 64 + ld0 + 16 * rg) * 8 + 4 * hi] = o1;
    }
  }
}

extern "C" void kernel_launch(void* const* d_in, const int* in_sizes, int n_in,
                              void* d_out, int out_size, void* d_ws, size_t ws_size,
                              hipStream_t stream) {
  const float* x = (const float*)d_in[0];
  const float* wqkv = (const float*)d_in[1];
  const float* wproj = (const float*)d_in[2];
  const float* bproj = (const float*)d_in[3];
  float* out = (float*)d_out;

  unsigned short* apack = (unsigned short*)d_ws;         // 8192*1024
  unsigned short* bpack = apack + (size_t)8192 * 1024;   // 3072*1024
  unsigned short* wprojp = bpack + (size_t)3072 * 1024;  // 1024*1024
  unsigned short* qbuf = wprojp + (size_t)1024 * 1024;   // 8192*1024
  unsigned short* kfb = qbuf + (size_t)8192 * 1024;      // 64*64*2048
  unsigned short* vfb = kfb + (size_t)64 * 64 * 2048;    // 64*64*2048
  unsigned short* attf = vfb + (size_t)64 * 64 * 2048;   // 8192*1024 (A-frag layout)

  pack3_kernel<<<6144, 256, 0, stream>>>(x, wqkv, wproj, apack, bpack, wprojp);

  gemm_fd<<<1536, 256, 0, stream>>>(apack, bpack, qbuf, kfb, vfb);

  attn_kernel<<<512, 256, 0, stream>>>(qbuf, kfb, vfb, attf);

  gemm_pd<<<512, 256, 0, stream>>>(attf, wprojp, bproj, out);
}